// Round 15
// baseline (47.210 us; speedup 1.0000x reference)
//
#include <hip/hip_runtime.h>
#include <math.h>

#define B 128
#define E 6
#define IN_DIM 1664
#define H_DIM 512
#define OUT_DIM 618
#define ZD 32
#define K2 544
#define S1 26             // L1 split-K (KPB=2)
#define S23 17            // L2/L3 split-K (16x1kb + 1 z-split)

typedef __attribute__((ext_vector_type(8))) short short8;
typedef __attribute__((ext_vector_type(4))) float f32x4;
union U128 { uint4 u4; short8 s8; ushort us[8]; };

__device__ __forceinline__ ushort f2bf(float f) {   // fp32 -> bf16 RNE
    uint u = __float_as_uint(f);
    u += 0x7fffu + ((u >> 16) & 1u);
    return (ushort)(u >> 16);
}
__device__ __forceinline__ uint pk2(float a, float b) {
    return (uint)f2bf(a) | ((uint)f2bf(b) << 16);
}
__device__ __forceinline__ float elu1(float x) { return x < 0.f ? expm1f(x) : x; }

// MFMA frag math (HW-validated r3-r14):
//  A frag (kb,m): lane l -> row 16m+(l&15), k = 32kb+(l>>4)*8+j
//  B frag (kb,nf): lane l -> col 16nf+(l&15), k = 32kb+(l>>4)*8+j
//  C/D: col = l&15, row = (l>>4)*4 + r
// Staging (validated r14): thread (tn=tid&15, tq=tid>>4) stages k=2tq,2tq+1
//  col n0+tn as one packed uint at lane ((tq>>2)<<4)|tn, j0=(2tq)&7.

// ---------------------------------------------------------------------------
// init_bias: y1,y2,out <- coef-blended biases. Gemms atomically accumulate
// on top (fence-free device-scope atomics); consumers apply elu inline.
// ---------------------------------------------------------------------------
__global__ __launch_bounds__(256) void init_bias(
    const float* __restrict__ coef,
    const float* __restrict__ b1, const float* __restrict__ b2,
    const float* __restrict__ b3,
    float* __restrict__ y1, float* __restrict__ y2, float* __restrict__ out)
{
    const int idx = blockIdx.x * 256 + threadIdx.x;
    if (idx >= B * (2 * H_DIM + OUT_DIM)) return;
    const int b = idx / (2 * H_DIM + OUT_DIM);
    const int o = idx - b * (2 * H_DIM + OUT_DIM);
    float ce[E];
    #pragma unroll
    for (int e = 0; e < E; ++e) ce[e] = coef[b * E + e];
    float v = 0.f;
    if (o < H_DIM) {
        #pragma unroll
        for (int e = 0; e < E; ++e) v = fmaf(ce[e], b1[e * H_DIM + o], v);
        y1[b * H_DIM + o] = v;
    } else if (o < 2 * H_DIM) {
        const int oo = o - H_DIM;
        #pragma unroll
        for (int e = 0; e < E; ++e) v = fmaf(ce[e], b2[e * H_DIM + oo], v);
        y2[b * H_DIM + oo] = v;
    } else {
        const int oo = o - 2 * H_DIM;
        #pragma unroll
        for (int e = 0; e < E; ++e) v = fmaf(ce[e], b3[e * OUT_DIM + oo], v);
        out[b * OUT_DIM + oo] = v;
    }
}

// ---------------------------------------------------------------------------
// gemm1: L1, block tile 128 rows x 16 cols, KPB=2 (12 steps), grid 32x26.
// SINGLE-BARRIER pipeline: issue ALL 24 W loads up front (wreg[12][2]),
// stage ALL 12 step-tiles into LDS (progressive vmcnt waits), ONE
// __syncthreads, then a barrier-free MFMA stream (ds_read + A-frag VALU).
// One latency exposure per block instead of 12. Epilogue: atomicAdd.
// ---------------------------------------------------------------------------
__global__ __launch_bounds__(256) void gemm1(
    const float* __restrict__ x,     // [B][IN_DIM]
    const float* __restrict__ coef,  // [B][E]
    const float* __restrict__ w,     // [E][IN_DIM][H_DIM]
    float* __restrict__ y1)          // [B][H_DIM] accum (bias pre-init)
{
    constexpr int NS = E * 2;        // 12 steps
    const int tid = threadIdx.x;
    const int l = tid & 63, wv = tid >> 6;
    const int n0 = blockIdx.x * 16, kb0 = blockIdx.y * 2;
    const int tn = tid & 15, tq = tid >> 4;
    const int lp = ((tq >> 2) << 4) | tn;
    const int j0 = (2 * tq) & 7;
    const int row0 = 32 * wv + (l & 15), row1 = row0 + 16, kq = l >> 4;

    __shared__ ushort bs[NS][64][8];                 // 12 KB, single-buffered

    // ---- issue ALL loads up front (all independent, all outstanding) ----
    float wreg[NS][2];
    #pragma unroll
    for (int s = 0; s < NS; ++s) {
        const int e = s % E, kb = kb0 + s / E;
        const float* src = w + ((size_t)e * IN_DIM + kb * 32 + 2 * tq) * H_DIM + n0 + tn;
        wreg[s][0] = src[0];
        wreg[s][1] = src[H_DIM];
    }
    float4 xreg[2][4];
    #pragma unroll
    for (int kbi = 0; kbi < 2; ++kbi) {
        const float* p0 = x + (size_t)row0 * IN_DIM + (kb0 + kbi) * 32 + kq * 8;
        const float* p1 = x + (size_t)row1 * IN_DIM + (kb0 + kbi) * 32 + kq * 8;
        xreg[kbi][0] = *reinterpret_cast<const float4*>(p0);
        xreg[kbi][1] = *reinterpret_cast<const float4*>(p0 + 4);
        xreg[kbi][2] = *reinterpret_cast<const float4*>(p1);
        xreg[kbi][3] = *reinterpret_cast<const float4*>(p1 + 4);
    }
    float ce0[E], ce1[E];
    #pragma unroll
    for (int e = 0; e < E; ++e) {
        ce0[e] = coef[row0 * E + e];
        ce1[e] = coef[row1 * E + e];
    }

    // ---- stage everything, ONE barrier ----
    #pragma unroll
    for (int s = 0; s < NS; ++s)
        *reinterpret_cast<uint*>(&bs[s][lp][j0]) = pk2(wreg[s][0], wreg[s][1]);
    __syncthreads();

    // ---- barrier-free compute stream ----
    f32x4 acc0 = {0.f,0.f,0.f,0.f}, acc1 = {0.f,0.f,0.f,0.f};
    #pragma unroll
    for (int s = 0; s < NS; ++s) {
        const int e = s % E, kbi = s / E;
        const float4* xc = xreg[kbi];
        U128 a0, a1;
        a0.us[0] = f2bf(xc[0].x * ce0[e]); a0.us[1] = f2bf(xc[0].y * ce0[e]);
        a0.us[2] = f2bf(xc[0].z * ce0[e]); a0.us[3] = f2bf(xc[0].w * ce0[e]);
        a0.us[4] = f2bf(xc[1].x * ce0[e]); a0.us[5] = f2bf(xc[1].y * ce0[e]);
        a0.us[6] = f2bf(xc[1].z * ce0[e]); a0.us[7] = f2bf(xc[1].w * ce0[e]);
        a1.us[0] = f2bf(xc[2].x * ce1[e]); a1.us[1] = f2bf(xc[2].y * ce1[e]);
        a1.us[2] = f2bf(xc[2].z * ce1[e]); a1.us[3] = f2bf(xc[2].w * ce1[e]);
        a1.us[4] = f2bf(xc[3].x * ce1[e]); a1.us[5] = f2bf(xc[3].y * ce1[e]);
        a1.us[6] = f2bf(xc[3].z * ce1[e]); a1.us[7] = f2bf(xc[3].w * ce1[e]);

        U128 b0;
        b0.u4 = *reinterpret_cast<const uint4*>(&bs[s][l][0]);
        acc0 = __builtin_amdgcn_mfma_f32_16x16x32_bf16(a0.s8, b0.s8, acc0, 0, 0, 0);
        acc1 = __builtin_amdgcn_mfma_f32_16x16x32_bf16(a1.s8, b0.s8, acc1, 0, 0, 0);
    }

    const int colB = n0 + (l & 15);
    const int rsub = (l >> 4) << 2;
    #pragma unroll
    for (int mi = 0; mi < 2; ++mi) {
        const int row = wv * 32 + mi * 16 + rsub;
        const f32x4 c = mi ? acc1 : acc0;
        #pragma unroll
        for (int r = 0; r < 4; ++r)
            atomicAdd(&y1[(size_t)(row + r) * H_DIM + colB], c[r]);
    }
}

// ---------------------------------------------------------------------------
// gemm_mid: L2/L3, block tile 128 x 16, KPB=1 (6 steps), 17 splits (16 + z).
// Same single-barrier pipeline (wreg[6][2], 6 KB LDS). Prologue: O(1) loads
// (elu(yin) or raw z), issued alongside the W loads. Epilogue: atomicAdd.
// ---------------------------------------------------------------------------
template<bool ZS, int NW, bool GUARD>
__device__ __forceinline__ void gemm_mid_body(
    const float* __restrict__ yin,   // [B][H_DIM] accum(+bias) pre-ELU
    const float* __restrict__ coef,  // [B][E]
    const float* __restrict__ z,     // [B][ZD]
    const float* __restrict__ w,     // [E][K2][NW]
    float* __restrict__ yout,        // [B][NW] accum (bias pre-init)
    int nt, int kb0, ushort (*bs)[64][8])
{
    constexpr int NS = E;            // 6 steps
    const int tid = threadIdx.x;
    const int l = tid & 63, wv = tid >> 6;
    const int n0 = nt * 16;
    const int tn = tid & 15, tq = tid >> 4;
    const int lp = ((tq >> 2) << 4) | tn;
    const int j0 = (2 * tq) & 7;
    const int row0 = 32 * wv + (l & 15), row1 = row0 + 16, kq = l >> 4;
    const bool okS = !GUARD || (n0 + tn) < NW;
    const bool okC = !GUARD || (n0 + (l & 15)) < NW;

    // ---- issue ALL W loads up front ----
    float wreg[NS][2];
    #pragma unroll
    for (int s = 0; s < NS; ++s) {
        const float* src = w + ((size_t)s * K2 + kb0 * 32 + 2 * tq) * NW + n0 + tn;
        wreg[s][0] = okS ? src[0] : 0.f;
        wreg[s][1] = okS ? src[NW] : 0.f;
    }

    float ce0[E], ce1[E];
    #pragma unroll
    for (int e = 0; e < E; ++e) {
        ce0[e] = coef[row0 * E + e];
        ce1[e] = coef[row1 * E + e];
    }

    // ---- prologue: per-thread activations (8 values), also up front ----
    float v0[8], v1[8];
    if (ZS) {
        const float4 za = *reinterpret_cast<const float4*>(z + row0 * ZD + kq * 8);
        const float4 zb = *reinterpret_cast<const float4*>(z + row0 * ZD + kq * 8 + 4);
        const float4 zc = *reinterpret_cast<const float4*>(z + row1 * ZD + kq * 8);
        const float4 zd = *reinterpret_cast<const float4*>(z + row1 * ZD + kq * 8 + 4);
        v0[0]=za.x; v0[1]=za.y; v0[2]=za.z; v0[3]=za.w;
        v0[4]=zb.x; v0[5]=zb.y; v0[6]=zb.z; v0[7]=zb.w;
        v1[0]=zc.x; v1[1]=zc.y; v1[2]=zc.z; v1[3]=zc.w;
        v1[4]=zd.x; v1[5]=zd.y; v1[6]=zd.z; v1[7]=zd.w;
    } else {
        const int kk = kb0 * 32 + kq * 8;
        const float* p0 = yin + (size_t)row0 * H_DIM + kk;
        const float* p1 = yin + (size_t)row1 * H_DIM + kk;
        const float4 a = *reinterpret_cast<const float4*>(p0);
        const float4 b = *reinterpret_cast<const float4*>(p0 + 4);
        const float4 c = *reinterpret_cast<const float4*>(p1);
        const float4 d = *reinterpret_cast<const float4*>(p1 + 4);
        v0[0]=elu1(a.x); v0[1]=elu1(a.y); v0[2]=elu1(a.z); v0[3]=elu1(a.w);
        v0[4]=elu1(b.x); v0[5]=elu1(b.y); v0[6]=elu1(b.z); v0[7]=elu1(b.w);
        v1[0]=elu1(c.x); v1[1]=elu1(c.y); v1[2]=elu1(c.z); v1[3]=elu1(c.w);
        v1[4]=elu1(d.x); v1[5]=elu1(d.y); v1[6]=elu1(d.z); v1[7]=elu1(d.w);
    }

    // ---- stage everything, ONE barrier ----
    #pragma unroll
    for (int s = 0; s < NS; ++s)
        *reinterpret_cast<uint*>(&bs[s][lp][j0]) = pk2(wreg[s][0], wreg[s][1]);
    __syncthreads();

    // ---- barrier-free compute stream ----
    f32x4 acc0 = {0.f,0.f,0.f,0.f}, acc1 = {0.f,0.f,0.f,0.f};
    #pragma unroll
    for (int s = 0; s < NS; ++s) {
        U128 a0, a1;
        #pragma unroll
        for (int j = 0; j < 8; ++j) {
            a0.us[j] = f2bf(v0[j] * ce0[s]);
            a1.us[j] = f2bf(v1[j] * ce1[s]);
        }
        U128 b0;
        b0.u4 = *reinterpret_cast<const uint4*>(&bs[s][l][0]);
        acc0 = __builtin_amdgcn_mfma_f32_16x16x32_bf16(a0.s8, b0.s8, acc0, 0, 0, 0);
        acc1 = __builtin_amdgcn_mfma_f32_16x16x32_bf16(a1.s8, b0.s8, acc1, 0, 0, 0);
    }

    const int colB = n0 + (l & 15);
    const int rsub = (l >> 4) << 2;
    #pragma unroll
    for (int mi = 0; mi < 2; ++mi) {
        const int row = wv * 32 + mi * 16 + rsub;
        const f32x4 c = mi ? acc1 : acc0;
        #pragma unroll
        for (int r = 0; r < 4; ++r)
            if (okC) atomicAdd(&yout[(size_t)(row + r) * NW + colB], c[r]);
    }
}

__global__ __launch_bounds__(256) void gemm_l2(
    const float* __restrict__ y1, const float* __restrict__ coef,
    const float* __restrict__ z, const float* __restrict__ w2,
    float* __restrict__ y2)
{
    __shared__ ushort bs[E][64][8];
    const int nt = blockIdx.x, sp = blockIdx.y;
    if (sp < 16)
        gemm_mid_body<false, H_DIM, false>(y1, coef, z, w2, y2, nt, sp, bs);
    else
        gemm_mid_body<true, H_DIM, false>(y1, coef, z, w2, y2, nt, 16, bs);
}

__global__ __launch_bounds__(256) void gemm_l3(
    const float* __restrict__ y2, const float* __restrict__ coef,
    const float* __restrict__ z, const float* __restrict__ w3,
    float* __restrict__ out)
{
    __shared__ ushort bs[E][64][8];
    const int nt = blockIdx.x, sp = blockIdx.y;
    if (sp < 16)
        gemm_mid_body<false, OUT_DIM, true>(y2, coef, z, w3, out, nt, sp, bs);
    else
        gemm_mid_body<true, OUT_DIM, true>(y2, coef, z, w3, out, nt, 16, bs);
}

extern "C" void kernel_launch(void* const* d_in, const int* in_sizes, int n_in,
                              void* d_out, int out_size, void* d_ws, size_t ws_size,
                              hipStream_t stream)
{
    const float* p_prev = (const float*)d_in[0];
    const float* coef   = (const float*)d_in[1];
    const float* z      = (const float*)d_in[2];
    const float* w1     = (const float*)d_in[3];
    const float* b1     = (const float*)d_in[4];
    const float* w2     = (const float*)d_in[5];
    const float* b2     = (const float*)d_in[6];
    const float* w3     = (const float*)d_in[7];
    const float* b3     = (const float*)d_in[8];
    float* out = (float*)d_out;

    // ws: y1 | y2 (fp32 accumulators, re-initialized every call by init_bias)
    float* y1 = (float*)d_ws;            // [B][512]
    float* y2 = y1 + (size_t)B * H_DIM;  // [B][512]

    const int TOT = B * (2 * H_DIM + OUT_DIM);
    init_bias<<<(TOT + 255) / 256, 256, 0, stream>>>(coef, b1, b2, b3, y1, y2, out);
    gemm1<<<dim3(32, S1), 256, 0, stream>>>(p_prev, coef, w1, y1);
    gemm_l2<<<dim3(32, S23), 256, 0, stream>>>(y1, coef, z, w2, y2);
    gemm_l3<<<dim3(39, S23), 256, 0, stream>>>(y2, coef, z, w3, out);
}

// Round 16
// 41.456 us; speedup vs baseline: 1.1388x; 1.1388x over previous
//
#include <hip/hip_runtime.h>
#include <math.h>

#define B 128
#define E 6
#define IN_DIM 1664
#define H_DIM 512
#define OUT_DIM 618
#define ZD 32
#define K2 544

typedef __attribute__((ext_vector_type(8))) short short8;
typedef __attribute__((ext_vector_type(4))) float f32x4;
union U128 { uint4 u4; short8 s8; ushort us[8]; };

__device__ __forceinline__ ushort f2bf(float f) {   // fp32 -> bf16 RNE
    uint u = __float_as_uint(f);
    u += 0x7fffu + ((u >> 16) & 1u);
    return (ushort)(u >> 16);
}
__device__ __forceinline__ uint pk2(float a, float b) {
    return (uint)f2bf(a) | ((uint)f2bf(b) << 16);
}
__device__ __forceinline__ float elu1(float x) { return x < 0.f ? expm1f(x) : x; }

// MFMA frag math (HW-validated r3-r15):
//  A frag: lane l -> row base+(l&15), k = 32kb+(l>>4)*8+j
//  B frag: lane l -> col n0+(l&15),   k = 32kb+(l>>4)*8+j
//  C/D: col = l&15, row = (l>>4)*4 + r
// B staging (validated r14): thread (tn=tid&15, tq=tid>>4) stages col n0+tn,
//  k-pair (2tq,2tq+1) as one packed uint at lane ((tq>>2)<<4)|tn, j0=(2tq)&7.
// NEW this round: 64-row block tile (1 M-frag/wave, 1 MFMA/step) -> same
// occupancy at HALF the split count -> half the atomic RMW total.

// ---------------------------------------------------------------------------
// init_y1: y1 <- coef-blended b1 (one float4/thread, 64 blocks).
// y2/out bias-init is folded into gemm1's blockIdx.y==0 slice.
// ---------------------------------------------------------------------------
__global__ __launch_bounds__(256) void init_y1(
    const float* __restrict__ coef, const float* __restrict__ b1,
    float* __restrict__ y1)
{
    const int t = blockIdx.x * 256 + threadIdx.x;    // 16384 = B*H_DIM/4
    const int b = t >> 7, o = (t & 127) << 2;
    float4 v = {0.f, 0.f, 0.f, 0.f};
    #pragma unroll
    for (int e = 0; e < E; ++e) {
        const float c = coef[b * E + e];
        const float4 bb = *reinterpret_cast<const float4*>(b1 + e * H_DIM + o);
        v.x = fmaf(c, bb.x, v.x); v.y = fmaf(c, bb.y, v.y);
        v.z = fmaf(c, bb.z, v.z); v.w = fmaf(c, bb.w, v.w);
    }
    *reinterpret_cast<float4*>(y1 + b * H_DIM + o) = v;
}

// ---------------------------------------------------------------------------
// gemm1: L1. Block tile 64 rows x 16 cols, KPB=4 (24 steps), grid (64, 14):
// y==0 -> bias-init slice for y2+out (runs concurrently; ordered before its
// consumers by the kernel boundary); y in [1,13] -> split kb0=(y-1)*4.
// W staged in 2 batches of 12 step-tiles (reg pressure), ONE barrier, then a
// barrier-free 24-MFMA stream. Epilogue: 4 atomicAdds/thread into y1.
// ---------------------------------------------------------------------------
__global__ __launch_bounds__(256) void gemm1(
    const float* __restrict__ x,     // [B][IN_DIM]
    const float* __restrict__ coef,  // [B][E]
    const float* __restrict__ w,     // [E][IN_DIM][H_DIM]
    const float* __restrict__ b2, const float* __restrict__ b3,
    float* __restrict__ y1, float* __restrict__ y2, float* __restrict__ out)
{
    __shared__ ushort bs[24][64][8];                 // 24 KB
    const int tid = threadIdx.x;

    if (blockIdx.y == 0) {                           // ---- init slice ----
        const int t = blockIdx.x * 256 + tid;        // 16384 threads
        {   // y2: exactly one float4 each
            const int b = t >> 7, o = (t & 127) << 2;
            float4 v = {0.f, 0.f, 0.f, 0.f};
            #pragma unroll
            for (int e = 0; e < E; ++e) {
                const float c = coef[b * E + e];
                const float4 bb = *reinterpret_cast<const float4*>(b2 + e * H_DIM + o);
                v.x = fmaf(c, bb.x, v.x); v.y = fmaf(c, bb.y, v.y);
                v.z = fmaf(c, bb.z, v.z); v.w = fmaf(c, bb.w, v.w);
            }
            *reinterpret_cast<float4*>(y2 + b * H_DIM + o) = v;
        }
        for (int i = t; i < B * OUT_DIM; i += 64 * 256) {
            const int b = i / OUT_DIM, o = i - b * OUT_DIM;
            float v = 0.f;
            #pragma unroll
            for (int e = 0; e < E; ++e)
                v = fmaf(coef[b * E + e], b3[e * OUT_DIM + o], v);
            out[i] = v;
        }
        return;
    }

    const int kb0 = (blockIdx.y - 1) * 4;
    const int n0 = (blockIdx.x & 31) * 16, rowbase = (blockIdx.x >> 5) * 64;
    const int l = tid & 63, wv = tid >> 6;
    const int tn = tid & 15, tq = tid >> 4;
    const int lp = ((tq >> 2) << 4) | tn, j0 = (2 * tq) & 7;
    const int row = rowbase + wv * 16 + (l & 15);
    const int kq = l >> 4;

    float ce[E];
    #pragma unroll
    for (int e = 0; e < E; ++e) ce[e] = coef[row * E + e];

    float xv[4][8];
    #pragma unroll
    for (int kbi = 0; kbi < 4; ++kbi) {
        const float* p = x + (size_t)row * IN_DIM + (kb0 + kbi) * 32 + kq * 8;
        const float4 a = *reinterpret_cast<const float4*>(p);
        const float4 b = *reinterpret_cast<const float4*>(p + 4);
        xv[kbi][0] = a.x; xv[kbi][1] = a.y; xv[kbi][2] = a.z; xv[kbi][3] = a.w;
        xv[kbi][4] = b.x; xv[kbi][5] = b.y; xv[kbi][6] = b.z; xv[kbi][7] = b.w;
    }

    #pragma unroll
    for (int bb = 0; bb < 2; ++bb) {                 // 2 batches of 12 tiles
        float wr[12][2];
        #pragma unroll
        for (int ss = 0; ss < 12; ++ss) {
            const int s = bb * 12 + ss;
            const int e = s % E, kb = kb0 + s / E;
            const float* src = w + ((size_t)e * IN_DIM + kb * 32 + 2 * tq) * H_DIM + n0 + tn;
            wr[ss][0] = src[0];
            wr[ss][1] = src[H_DIM];
        }
        #pragma unroll
        for (int ss = 0; ss < 12; ++ss)
            *reinterpret_cast<uint*>(&bs[bb * 12 + ss][lp][j0]) =
                pk2(wr[ss][0], wr[ss][1]);
    }
    __syncthreads();

    f32x4 acc = {0.f, 0.f, 0.f, 0.f};
    #pragma unroll
    for (int s = 0; s < 24; ++s) {
        const int e = s % E, kbi = s / E;
        U128 a, b0;
        #pragma unroll
        for (int j = 0; j < 8; ++j) a.us[j] = f2bf(xv[kbi][j] * ce[e]);
        b0.u4 = *reinterpret_cast<const uint4*>(&bs[s][l][0]);
        acc = __builtin_amdgcn_mfma_f32_16x16x32_bf16(a.s8, b0.s8, acc, 0, 0, 0);
    }

    const int colB = n0 + (l & 15);
    const int rowE = rowbase + wv * 16 + ((l >> 4) << 2);
    #pragma unroll
    for (int r = 0; r < 4; ++r)
        atomicAdd(&y1[(size_t)(rowE + r) * H_DIM + colB], acc[r]);
}

// ---------------------------------------------------------------------------
// gemm_mid: L2/L3. Block tile 64 x 16, S23=9 (8 splits of 2kb + 1 z-split).
// Prologue: O(1) loads (elu(yin) or raw z). All W tiles loaded+staged, one
// barrier, barrier-free MFMA stream. Epilogue: 4 atomicAdds/thread.
// ---------------------------------------------------------------------------
template<int KPB, bool ZS, int NW, bool GUARD>
__device__ __forceinline__ void gemm_mid_body(
    const float* __restrict__ yin,   // [B][H_DIM] accum(+bias) pre-ELU
    const float* __restrict__ coef,  // [B][E]
    const float* __restrict__ z,     // [B][ZD]
    const float* __restrict__ w,     // [E][K2][NW]
    float* __restrict__ yout,        // [B][NW] accum (bias pre-init)
    int n0, int rowbase, int kb0, ushort (*bs)[64][8])
{
    constexpr int NS = E * KPB;
    const int tid = threadIdx.x;
    const int l = tid & 63, wv = tid >> 6;
    const int tn = tid & 15, tq = tid >> 4;
    const int lp = ((tq >> 2) << 4) | tn, j0 = (2 * tq) & 7;
    const int row = rowbase + wv * 16 + (l & 15);
    const int kq = l >> 4;
    const bool okS = !GUARD || (n0 + tn) < NW;

    float wr[NS][2];
    #pragma unroll
    for (int s = 0; s < NS; ++s) {
        const int e = s % E, kb = kb0 + s / E;
        const float* src = w + ((size_t)e * K2 + kb * 32 + 2 * tq) * NW + n0 + tn;
        wr[s][0] = okS ? src[0] : 0.f;
        wr[s][1] = okS ? src[NW] : 0.f;
    }

    float ce[E];
    #pragma unroll
    for (int e = 0; e < E; ++e) ce[e] = coef[row * E + e];

    float v[KPB * 8];
    if (ZS) {
        const float4 a = *reinterpret_cast<const float4*>(z + row * ZD + kq * 8);
        const float4 b = *reinterpret_cast<const float4*>(z + row * ZD + kq * 8 + 4);
        v[0] = a.x; v[1] = a.y; v[2] = a.z; v[3] = a.w;
        v[4] = b.x; v[5] = b.y; v[6] = b.z; v[7] = b.w;
    } else {
        #pragma unroll
        for (int kbi = 0; kbi < KPB; ++kbi) {
            const float* p = yin + (size_t)row * H_DIM + (kb0 + kbi) * 32 + kq * 8;
            const float4 a = *reinterpret_cast<const float4*>(p);
            const float4 b = *reinterpret_cast<const float4*>(p + 4);
            v[kbi*8+0] = elu1(a.x); v[kbi*8+1] = elu1(a.y);
            v[kbi*8+2] = elu1(a.z); v[kbi*8+3] = elu1(a.w);
            v[kbi*8+4] = elu1(b.x); v[kbi*8+5] = elu1(b.y);
            v[kbi*8+6] = elu1(b.z); v[kbi*8+7] = elu1(b.w);
        }
    }

    #pragma unroll
    for (int s = 0; s < NS; ++s)
        *reinterpret_cast<uint*>(&bs[s][lp][j0]) = pk2(wr[s][0], wr[s][1]);
    __syncthreads();

    f32x4 acc = {0.f, 0.f, 0.f, 0.f};
    #pragma unroll
    for (int s = 0; s < NS; ++s) {
        const int e = s % E, kbi = s / E;
        U128 a, b0;
        #pragma unroll
        for (int j = 0; j < 8; ++j) a.us[j] = f2bf(v[kbi * 8 + j] * ce[e]);
        b0.u4 = *reinterpret_cast<const uint4*>(&bs[s][l][0]);
        acc = __builtin_amdgcn_mfma_f32_16x16x32_bf16(a.s8, b0.s8, acc, 0, 0, 0);
    }

    const int colB = n0 + (l & 15);
    const int rowE = rowbase + wv * 16 + ((l >> 4) << 2);
    if (!GUARD || colB < NW) {
        #pragma unroll
        for (int r = 0; r < 4; ++r)
            atomicAdd(&yout[(size_t)(rowE + r) * NW + colB], acc[r]);
    }
}

__global__ __launch_bounds__(256) void gemm_l2(
    const float* __restrict__ y1, const float* __restrict__ coef,
    const float* __restrict__ z, const float* __restrict__ w2,
    float* __restrict__ y2)
{
    __shared__ ushort bs[12][64][8];                 // 12 KB
    const int n0 = (blockIdx.x & 31) * 16, rowbase = (blockIdx.x >> 5) * 64;
    const int sp = blockIdx.y;
    if (sp < 8)
        gemm_mid_body<2, false, H_DIM, false>(y1, coef, z, w2, y2,
                                              n0, rowbase, sp * 2, bs);
    else
        gemm_mid_body<1, true, H_DIM, false>(y1, coef, z, w2, y2,
                                             n0, rowbase, 16, bs);
}

__global__ __launch_bounds__(256) void gemm_l3(
    const float* __restrict__ y2, const float* __restrict__ coef,
    const float* __restrict__ z, const float* __restrict__ w3,
    float* __restrict__ out)
{
    __shared__ ushort bs[12][64][8];
    const int nt = blockIdx.x % 40, rt = blockIdx.x / 40;   // 40 col-tiles
    const int n0 = nt * 16, rowbase = rt * 64;
    const int sp = blockIdx.y;
    if (sp < 8)
        gemm_mid_body<2, false, OUT_DIM, true>(y2, coef, z, w3, out,
                                               n0, rowbase, sp * 2, bs);
    else
        gemm_mid_body<1, true, OUT_DIM, true>(y2, coef, z, w3, out,
                                              n0, rowbase, 16, bs);
}

extern "C" void kernel_launch(void* const* d_in, const int* in_sizes, int n_in,
                              void* d_out, int out_size, void* d_ws, size_t ws_size,
                              hipStream_t stream)
{
    const float* p_prev = (const float*)d_in[0];
    const float* coef   = (const float*)d_in[1];
    const float* z      = (const float*)d_in[2];
    const float* w1     = (const float*)d_in[3];
    const float* b1     = (const float*)d_in[4];
    const float* w2     = (const float*)d_in[5];
    const float* b2     = (const float*)d_in[6];
    const float* w3     = (const float*)d_in[7];
    const float* b3     = (const float*)d_in[8];
    float* out = (float*)d_out;

    // ws: y1 | y2 (fp32 accumulators, re-initialized every call)
    float* y1 = (float*)d_ws;            // [B][512]
    float* y2 = y1 + (size_t)B * H_DIM;  // [B][512]

    init_y1<<<64, 256, 0, stream>>>(coef, b1, y1);
    // y==0: bias-init slice (y2, out); y in [1,13]: L1 splits (S1=13, KPB=4)
    gemm1<<<dim3(64, 14), 256, 0, stream>>>(p_prev, coef, w1, b2, b3,
                                            y1, y2, out);
    gemm_l2<<<dim3(64, 9), 256, 0, stream>>>(y1, coef, z, w2, y2);
    gemm_l3<<<dim3(80, 9), 256, 0, stream>>>(y2, coef, z, w3, out);
}